// Round 3
// baseline (4358.168 us; speedup 1.0000x reference)
//
#include <hip/hip_runtime.h>
#include <hip/hip_bf16.h>
#include <stdint.h>
#include <stddef.h>

// Problem constants (B=32, T=256, E=H=1024)
#define TT    256
#define NBLK  128   // 64 layer0 blocks + 64 layer1 blocks, 4 waves each

typedef __attribute__((ext_vector_type(8))) short short8;
typedef __attribute__((ext_vector_type(4))) float f32x4;

// fp32 -> bf16 (RNE)
__device__ __forceinline__ short f2bf(float v) {
  uint32_t u = __builtin_bit_cast(uint32_t, v);
  uint32_t r = (u + 0x7fffu + ((u >> 16) & 1u)) >> 16;
  return (short)r;
}

// ---------------------------------------------------------------------------
// K0: mask passthrough output; zero h0-ring slot 127 + h1 ping-pong + barrier
// counters (contiguous 204800B region at ws+58654720).
// ---------------------------------------------------------------------------
__global__ void k_init(const float* __restrict__ mask, float* __restrict__ out,
                       uint32_t* __restrict__ z) {
  int tid = blockIdx.x * blockDim.x + threadIdx.x;   // 16384 threads
  if (tid < 8192) out[8388608 + tid] = mask[tid];
  for (int j = tid; j < 51200; j += 16384) z[j] = 0; // 64KB+128KB+8KB
}

// ---------------------------------------------------------------------------
// K1: pack weights into bf16 MFMA-B fragment order.
// Bp[wgid 0..511][f 0..63][lane 0..63][8 shorts], wgid = layer*256 + blk*4 + w
//  f = cg*16 + s;  k = w*512 + s*32 + (lane>>4)*8 + j  (B-frag: n=lane&15)
//  col = ((lane&15)>>2)*1024 + blk*16 + cg*4 + (lane&3)   (gate-interleaved)
// ---------------------------------------------------------------------------
__global__ void k_packw(const float* __restrict__ Wih0, const float* __restrict__ Whh0,
                        const float* __restrict__ Wih1, const float* __restrict__ Whh1,
                        short* __restrict__ Bp) {
  int cid = blockIdx.x * blockDim.x + threadIdx.x;   // 0 .. 2097151
  int l    = cid & 63;
  int f    = (cid >> 6) & 63;
  int wgid = cid >> 12;                               // 0..511
  int q  = l >> 4, cc = l & 15;
  int cg = f >> 4, s = f & 15;
  int w    = wgid & 3;
  int blk  = (wgid >> 2) & 63;
  bool p1  = (wgid >= 256);
  int precol = (cc >> 2) * 1024 + blk * 16 + cg * 4 + (cc & 3);
  const float* MA = p1 ? Wih1 : Wih0;
  const float* MB = p1 ? Whh1 : Whh0;
  short8 o;
#pragma unroll
  for (int j = 0; j < 8; ++j) {
    int k = w * 512 + s * 32 + q * 8 + j;            // 0..2047
    const float* M = (k < 1024) ? MA : MB;
    o[j] = f2bf(M[(size_t)(k & 1023) * 4096 + precol]);
  }
  ((short8*)Bp)[cid] = o;
}

// ---------------------------------------------------------------------------
// K2: convert x to bf16 blocked A-layout per t: Xb[t][kb][m=b][8]
// ---------------------------------------------------------------------------
__global__ void k_packx(const float* __restrict__ x, short* __restrict__ Xb) {
  int tid = blockIdx.x * blockDim.x + threadIdx.x;   // 0 .. 1048575
  int eg = tid & 127;
  int t  = (tid >> 7) & 255;
  int b  = tid >> 15;
  const float* src = x + ((size_t)(b * 256 + t) * 1024 + eg * 8);
  short8 o;
#pragma unroll
  for (int j = 0; j < 8; ++j) o[j] = f2bf(src[j]);
  ((short8*)Xb)[(t * 128 + eg) * 32 + b] = o;
}

// ---------------------------------------------------------------------------
// K3: persistent recurrent kernel. 128 blocks x 256 threads (4 waves).
// bid<64 -> layer0, bid>=64 -> layer1. Sync structure identical to R2
// (per-layer fan-in barrier, h0 ring, cross-layer epoch gates, skip-last).
//
// R3 CHANGE — h-panel reads go through L2 instead of per-lane MALL-coherent
// loads. R0/R2 re-read 12MB/step of h state as sc0sc1 8B atomics, i.e. ~98K
// line-requests/step concentrated on the ~1500 MALL lines of the tiny h
// panels -> multi-us slice queueing that also inflated every barrier RTT.
// Now: consumers issue ONE agent-scope acquire fence per step (buffer_inv
// sc1: invalidates clean L1+L2 lines, preserves dirty lines e.g. `out`),
// then plain global_load_dwordx4 reads. Blocks sharing an XCD share one L2
// fill per line (~10x fewer MALL requests) and VMEM op count halves.
// Correctness: producer h stores remain sc0sc1 write-through (MALL = point
// of truth, acked via vmcnt(0) BEFORE the arrival RMW -> epoch publish ->
// consumer detect -> fence-inv -> any post-inv L2 fill reads fresh MALL
// data). Ring/ping-pong address rotation means no in-flight stale fill can
// alias the panel being read.
// ---------------------------------------------------------------------------
__global__ __launch_bounds__(256, 1) void k_lstm(
    const float* __restrict__ mask, const float* __restrict__ b0,
    const float* __restrict__ b1,   const short* __restrict__ Bp,
    const short* __restrict__ Xb,   short* __restrict__ h0r,
    short* __restrict__ h1b,        float* __restrict__ out,
    uint32_t* bar) {
  __shared__ f32x4 xch[4][4][2][64];   // 32KB partial-sum exchange
  __shared__ short hstage[512];        // 1KB h repack staging

  const int tid  = threadIdx.x;
  const int wv   = tid >> 6;          // wave 0..3 (K-slice)
  const int lane = tid & 63;
  const int quad = lane >> 4;
  const int cc   = lane & 15;
  const int bid  = blockIdx.x;
  const bool is1 = (bid >= 64);
  const int blk  = bid & 63;
  const int wgid = (is1 ? 256 : 0) + blk * 4 + wv;
  const int n0w  = blk * 16 + wv * 4;             // h-col base for gating
  const int hcol = n0w + (cc & 3);
  const int kb0  = (wv & 1) * 64;                 // kb offset within source panel
  const bool coh = !(!is1 && wv < 2);             // this wave's A-source is an h panel

  // barrier layout (uints): layer L at L*1024:
  //   group g (0..7) at +g*32 (128B apart), master at +256, epoch at +512
  uint32_t* const barL   = bar + (is1 ? 1024 : 0);
  uint32_t* const grpC   = barL + (blk & 7) * 32;
  uint32_t* const mstC   = barL + 256;
  uint32_t* const epoL   = barL + 512;
  uint32_t* const epoO   = bar + (is1 ? 0 : 1024) + 512;

  // B fragments (64 KB) resident in registers
  short8 bfr[64];
  {
    const short8* pB = ((const short8*)Bp) + (size_t)wgid * 4096 + lane;
#pragma unroll
    for (int f = 0; f < 64; ++f) bfr[f] = pB[f * 64];
  }
  const float* bias = is1 ? b1 : b0;
  const float bv = bias[(cc >> 2) * 1024 + n0w + (cc & 3)];

  float cst[8], hst[8];
#pragma unroll
  for (int i = 0; i < 8; ++i) { cst[i] = 0.f; hst[i] = 0.f; }

  const int shuf_base = (lane & 48) | (lane & 3);
  const short8* Xq = (const short8*)Xb;
  const short8* H0 = (const short8*)h0r;
  const short8* H1 = (const short8*)h1b;

  // layer0's h0(255) is consumed by nobody -> it stops after step 254.
  const int tmax = is1 ? TT : (TT - 1);

  for (int t = 0; t < tmax; ++t) {
    const int p  = t & 1;              // h1 ping-pong read parity; write 1-p
    const int rs = (t + 127) & 127;    // h0 ring read slot = (t-1) mod 128

    const short8* pan;
    if (!is1) pan = (wv < 2) ? (Xq + (size_t)t * 4096) : (H0 + (size_t)rs * 4096);
    else      pan = (wv < 2) ? (H0 + (size_t)rs * 4096) : (H1 + p * 4096);

    // h-consuming waves: invalidate clean L1/L2 lines so the plain cached
    // loads below observe the producer's MALL write-through data. Placed
    // after the release __syncthreads (loop bottom) and before any h load.
    if (coh) __builtin_amdgcn_fence(__ATOMIC_ACQUIRE, "agent");

    f32x4 acc[4][2];
#pragma unroll
    for (int cg = 0; cg < 4; ++cg) { acc[cg][0] = (f32x4)0.f; acc[cg][1] = (f32x4)0.f; }

    float mrow[8];
#pragma unroll
    for (int i = 0; i < 8; ++i) {
      int r = ((i >> 2) << 4) + quad * 4 + (i & 3);
      mrow[i] = mask[r * 256 + t];
    }

#pragma unroll
    for (int s = 0; s < 16; ++s) {
      const short8* ap = pan + ((kb0 + s * 4 + quad) * 32 + cc);
      short8 a0 = ap[0];       // rows 0..15  (L2-cached dwordx4)
      short8 a1 = ap[16];      // rows 16..31
#pragma unroll
      for (int cg = 0; cg < 4; ++cg) {
        acc[cg][0] = __builtin_amdgcn_mfma_f32_16x16x32_bf16(a0, bfr[cg * 16 + s], acc[cg][0], 0, 0, 0);
        acc[cg][1] = __builtin_amdgcn_mfma_f32_16x16x32_bf16(a1, bfr[cg * 16 + s], acc[cg][1], 0, 0, 0);
      }
    }

    // ---- cross-wave K-reduction via LDS ----
#pragma unroll
    for (int cg = 0; cg < 4; ++cg) {
      if (cg != wv) {
        xch[wv][cg][0][lane] = acc[cg][0];
        xch[wv][cg][1][lane] = acc[cg][1];
      }
    }
    __syncthreads();
    f32x4 s0 = acc[wv][0], s1 = acc[wv][1];
#pragma unroll
    for (int w2 = 0; w2 < 4; ++w2) {
      if (w2 != wv) {
        s0 += xch[w2][wv][0][lane];
        s1 += xch[w2][wv][1][lane];
      }
    }

    float pv[8];
    pv[0] = s0.x + bv; pv[1] = s0.y + bv; pv[2] = s0.z + bv; pv[3] = s0.w + bv;
    pv[4] = s1.x + bv; pv[5] = s1.y + bv; pv[6] = s1.z + bv; pv[7] = s1.w + bv;

    // ---- gating (C/D: col = lane&15, row = quad*4 + reg) ----
#pragma unroll
    for (int i = 0; i < 8; ++i) {
      float v = pv[i];
      float fg = __shfl(v, shuf_base + 0, 64);
      float ig = __shfl(v, shuf_base + 4, 64);
      float og = __shfl(v, shuf_base + 8, 64);
      float gg = __shfl(v, shuf_base + 12, 64);
      int r = ((i >> 2) << 4) + quad * 4 + (i & 3);
      float m  = mrow[i];
      float om = 1.f - m;
      float sf = 1.f / (1.f + __expf(-fg));
      float si = 1.f / (1.f + __expf(-ig));
      float so = 1.f / (1.f + __expf(-og));
      float e2 = __expf(-2.f * fabsf(gg));
      float tg = (1.f - e2) / (1.f + e2);
      tg = (gg < 0.f) ? -tg : tg;
      float c1 = sf * cst[i] + si * tg;
      c1 = c1 * m + cst[i] * om;
      float ec = __expf(-2.f * fabsf(c1));
      float tc = (1.f - ec) / (1.f + ec);
      tc = (c1 < 0.f) ? -tc : tc;
      float h1 = so * tc;
      h1 = h1 * m + hst[i] * om;
      cst[i] = c1; hst[i] = h1;
      if ((lane & 12) == 0) {   // gate-f lanes: one writer per (h-col, row)
        int hl = wv * 4 + (cc & 3);                 // block-local h-col 0..15
        hstage[(hl >> 3) * 256 + r * 8 + (hl & 7)] = f2bf(h1);
        if (is1) out[((size_t)r * 256 + t) * 1024 + hcol] = h1;
      }
    }

    if (is1 && t == TT - 1) break;   // layer1 final step: no successor

    __syncthreads();   // hstage complete across all waves
    if (wv == 0) {     // packed MALL write-through h store: contiguous 1KB
      short* dst = (is1 ? (h1b + (1 - p) * 32768)
                        : (h0r + (t & 127) * 32768)) + blk * 512 + lane * 8;
      const uint64_t* sl = ((const uint64_t*)hstage) + lane * 2;
      uint64_t v0 = sl[0], v1 = sl[1];
      __hip_atomic_store((uint64_t*)dst,       v0, __ATOMIC_RELAXED, __HIP_MEMORY_SCOPE_AGENT);
      __hip_atomic_store(((uint64_t*)dst) + 1, v1, __ATOMIC_RELAXED, __HIP_MEMORY_SCOPE_AGENT);
    }

    // ---- per-layer fan-in barrier (R0 topology), epoch spin, gates ----
    if (tid == 0) {
      // drain wave0's h stores to MALL before the arrival is observable
      asm volatile("s_waitcnt vmcnt(0)" ::: "memory");
      uint32_t old = __hip_atomic_fetch_add(grpC, 1u,
                                            __ATOMIC_RELAXED, __HIP_MEMORY_SCOPE_AGENT);
      if ((old & 7) == 7) {   // last of 8 in group this step
        uint32_t mo = __hip_atomic_fetch_add(mstC, 1u,
                                             __ATOMIC_RELAXED, __HIP_MEMORY_SCOPE_AGENT);
        if ((mo & 7) == 7)    // last group -> publish epoch (write-once line)
          __hip_atomic_store(epoL, (uint32_t)(t + 1),
                             __ATOMIC_RELAXED, __HIP_MEMORY_SCOPE_AGENT);
      }
      if (t + 1 < tmax) {     // skip spins when about to exit
        const uint32_t need = (uint32_t)(t + 1);
        if (is1) {
          // own epoch + l0 epoch polled in the same iteration (1 RTT)
          for (;;) {
            uint32_t eL = __hip_atomic_load(epoL, __ATOMIC_RELAXED, __HIP_MEMORY_SCOPE_AGENT);
            uint32_t eO = __hip_atomic_load(epoO, __ATOMIC_RELAXED, __HIP_MEMORY_SCOPE_AGENT);
            if (eL >= need && eO >= need) break;
            __builtin_amdgcn_s_sleep(2);
          }
        } else if (t >= 127) {
          // ring safety: step t+1 overwrites h0(t-127), last read by l1 step
          // t-126 -> require epoch_l1 >= t-125. Slack ~126 steps.
          const uint32_t needO = (uint32_t)(t - 125);
          for (;;) {
            uint32_t eL = __hip_atomic_load(epoL, __ATOMIC_RELAXED, __HIP_MEMORY_SCOPE_AGENT);
            uint32_t eO = __hip_atomic_load(epoO, __ATOMIC_RELAXED, __HIP_MEMORY_SCOPE_AGENT);
            if (eL >= need && eO >= needO) break;
            __builtin_amdgcn_s_sleep(2);
          }
        } else {
          while (__hip_atomic_load(epoL, __ATOMIC_RELAXED, __HIP_MEMORY_SCOPE_AGENT) < need)
            __builtin_amdgcn_s_sleep(2);
        }
      }
    }
    __syncthreads();
  }
}

// ---------------------------------------------------------------------------
// Workspace layout (bytes):
//   [0, 32MB)            B_packed (512 waves x 64KB bf16)
//   [32MB, 48MB)         X blocked
//   [48MB, 56MB)         h0 ring: 128 slots x 64KB (slot = t & 127)
//   [56MB, 56MB+128KB)   h1 ping-pong (2 x 64KB)
//   [+8KB)               barrier (per layer: 8 group ctrs / master / epoch)
//   k_init zeroes [56MB-64KB, 56MB+136KB) = ring slot 127 + h1 + counters
// ---------------------------------------------------------------------------
extern "C" void kernel_launch(void* const* d_in, const int* in_sizes, int n_in,
                              void* d_out, int out_size, void* d_ws, size_t ws_size,
                              hipStream_t stream) {
  const float* x    = (const float*)d_in[0];
  const float* mask = (const float*)d_in[1];
  const float* Wih0 = (const float*)d_in[2];
  const float* Whh0 = (const float*)d_in[3];
  const float* b0   = (const float*)d_in[4];
  const float* Wih1 = (const float*)d_in[5];
  const float* Whh1 = (const float*)d_in[6];
  const float* b1   = (const float*)d_in[7];
  float* out = (float*)d_out;

  char* ws = (char*)d_ws;
  short*    Bp  = (short*)ws;
  short*    Xb  = (short*)(ws + 33554432);
  short*    h0r = (short*)(ws + 50331648);
  short*    h1b = (short*)(ws + 58720256);
  uint32_t* bar = (uint32_t*)(ws + 58851328);
  uint32_t* z   = (uint32_t*)(ws + 58654720);   // zero region base

  hipLaunchKernelGGL(k_init,  dim3(64),   dim3(256), 0, stream, mask, out, z);
  hipLaunchKernelGGL(k_packw, dim3(8192), dim3(256), 0, stream, Wih0, Whh0, Wih1, Whh1, Bp);
  hipLaunchKernelGGL(k_packx, dim3(4096), dim3(256), 0, stream, x, Xb);
  hipLaunchKernelGGL(k_lstm,  dim3(NBLK), dim3(256), 0, stream,
                     mask, b0, b1, Bp, Xb, h0r, h1b, out, bar);
}

// Round 4
// 2511.467 us; speedup vs baseline: 1.7353x; 1.7353x over previous
//
#include <hip/hip_runtime.h>
#include <hip/hip_bf16.h>
#include <stdint.h>
#include <stddef.h>

// Problem constants (B=32, T=256, E=H=1024)
#define TT    256
#define NBLK  128   // 64 layer0 blocks + 64 layer1 blocks, 4 waves each

typedef __attribute__((ext_vector_type(8))) short short8;
typedef __attribute__((ext_vector_type(4))) float f32x4;

// fp32 -> bf16 (RNE)
__device__ __forceinline__ short f2bf(float v) {
  uint32_t u = __builtin_bit_cast(uint32_t, v);
  uint32_t r = (u + 0x7fffu + ((u >> 16) & 1u)) >> 16;
  return (short)r;
}

// Direct global->LDS 16B stage. COH: CPol SC0|SC1 (=1|16) -> bypass L1/L2,
// read MALL (coherent with producer's sc0sc1 write-through stores).
__device__ __forceinline__ void stage_coh(const short8* g, short8* l) {
  __builtin_amdgcn_global_load_lds(
      (const __attribute__((address_space(1))) void*)g,
      (__attribute__((address_space(3))) void*)l, 16, 0, 17);
}
__device__ __forceinline__ void stage_pln(const short8* g, short8* l) {
  __builtin_amdgcn_global_load_lds(
      (const __attribute__((address_space(1))) void*)g,
      (__attribute__((address_space(3))) void*)l, 16, 0, 0);
}

// ---------------------------------------------------------------------------
// K0: mask passthrough output; zero h0-ring slot 127 + h1 ping-pong + barrier
// counters (contiguous 204800B region at ws+58654720).
// ---------------------------------------------------------------------------
__global__ void k_init(const float* __restrict__ mask, float* __restrict__ out,
                       uint32_t* __restrict__ z) {
  int tid = blockIdx.x * blockDim.x + threadIdx.x;   // 16384 threads
  if (tid < 8192) out[8388608 + tid] = mask[tid];
  for (int j = tid; j < 51200; j += 16384) z[j] = 0; // 64KB+128KB+8KB
}

// ---------------------------------------------------------------------------
// K1: pack weights into bf16 MFMA-B fragment order.
// Bp[wgid 0..511][f 0..63][lane 0..63][8 shorts], wgid = layer*256 + blk*4 + w
//  f = cg*16 + s;  k = w*512 + s*32 + (lane>>4)*8 + j  (B-frag: n=lane&15)
//  col = ((lane&15)>>2)*1024 + blk*16 + cg*4 + (lane&3)   (gate-interleaved)
// ---------------------------------------------------------------------------
__global__ void k_packw(const float* __restrict__ Wih0, const float* __restrict__ Whh0,
                        const float* __restrict__ Wih1, const float* __restrict__ Whh1,
                        short* __restrict__ Bp) {
  int cid = blockIdx.x * blockDim.x + threadIdx.x;   // 0 .. 2097151
  int l    = cid & 63;
  int f    = (cid >> 6) & 63;
  int wgid = cid >> 12;                               // 0..511
  int q  = l >> 4, cc = l & 15;
  int cg = f >> 4, s = f & 15;
  int w    = wgid & 3;
  int blk  = (wgid >> 2) & 63;
  bool p1  = (wgid >= 256);
  int precol = (cc >> 2) * 1024 + blk * 16 + cg * 4 + (cc & 3);
  const float* MA = p1 ? Wih1 : Wih0;
  const float* MB = p1 ? Whh1 : Whh0;
  short8 o;
#pragma unroll
  for (int j = 0; j < 8; ++j) {
    int k = w * 512 + s * 32 + q * 8 + j;            // 0..2047
    const float* M = (k < 1024) ? MA : MB;
    o[j] = f2bf(M[(size_t)(k & 1023) * 4096 + precol]);
  }
  ((short8*)Bp)[cid] = o;
}

// ---------------------------------------------------------------------------
// K2: convert x to bf16 blocked A-layout per t: Xb[t][kb][m=b][8]
// ---------------------------------------------------------------------------
__global__ void k_packx(const float* __restrict__ x, short* __restrict__ Xb) {
  int tid = blockIdx.x * blockDim.x + threadIdx.x;   // 0 .. 1048575
  int eg = tid & 127;
  int t  = (tid >> 7) & 255;
  int b  = tid >> 15;
  const float* src = x + ((size_t)(b * 256 + t) * 1024 + eg * 8);
  short8 o;
#pragma unroll
  for (int j = 0; j < 8; ++j) o[j] = f2bf(src[j]);
  ((short8*)Xb)[(t * 128 + eg) * 32 + b] = o;
}

// ---------------------------------------------------------------------------
// K3: persistent recurrent kernel. 128 blocks x 256 threads (4 waves).
// bid<64 -> layer0, bid>=64 -> layer1. Sync structure identical to R2
// (per-layer fan-in barrier, h0 ring, cross-layer epoch gates, skip-last).
//
// R4 CHANGE — A-panel loads are staged global->LDS via global_load_lds
// (register-free DMA, all 32 16B-ops in flight -> ~1 MALL RTT instead of
// 64 register-limited 8B atomics at depth ~10 = several us/step at
// 1 wave/SIMD occupancy where NO TLP hides latency). h panels use CPol
// SC0|SC1 (aux=17): bypass L1/L2, read MALL = coherent with the producer's
// sc0sc1 write-through stores (same semantics as the old per-lane agent
// atomics, 8x fewer MALL transactions since normal loads TA-coalesce).
// Xb waves stage with aux=0 (normally cached).
//   LDS: stg[8192] short8 = 128KB (wave wv stages its 32KB A-half at
//   wv*32KB). xch (32KB) and hstage (1KB) are OVERLAID into stg -- all
//   staged reads complete before xch writes (new sync#0), and hstage
//   (bytes 32768..33791) is consumed before next-step staging overwrites
//   it (wave0 reads it before the loop-end barrier).
// Per-wave ordering: s_waitcnt vmcnt(0) after staging (global_load_lds
// completion = LDS written), sched_barrier(0) fence, then ds_read/MFMA.
// Wave0's h-store widened to global_store_dwordx4 sc0 sc1 (1 op/lane).
// ---------------------------------------------------------------------------
__global__ __launch_bounds__(256, 1) void k_lstm(
    const float* __restrict__ mask, const float* __restrict__ b0,
    const float* __restrict__ b1,   const short* __restrict__ Bp,
    const short* __restrict__ Xb,   short* __restrict__ h0r,
    short* __restrict__ h1b,        float* __restrict__ out,
    uint32_t* bar) {
  __shared__ short8 stg[8192];         // 128KB: 4 waves x 32KB A-halves
  // overlays (temporally disjoint from staged-data lifetime):
  f32x4 (*xch)[4][2][64] = (f32x4 (*)[4][2][64])(void*)stg;   // 32KB @0
  short* hstage = (short*)(void*)(stg + 2048);                // 1KB  @32KB

  const int tid  = threadIdx.x;
  const int wv   = tid >> 6;          // wave 0..3 (K-slice)
  const int lane = tid & 63;
  const int quad = lane >> 4;
  const int cc   = lane & 15;
  const int bid  = blockIdx.x;
  const bool is1 = (bid >= 64);
  const int blk  = bid & 63;
  const int wgid = (is1 ? 256 : 0) + blk * 4 + wv;
  const int n0w  = blk * 16 + wv * 4;             // h-col base for gating
  const int hcol = n0w + (cc & 3);
  const int kb0  = (wv & 1) * 64;                 // kb offset within source panel
  const bool coh = !(!is1 && wv < 2);             // this wave's A-source is an h panel

  // barrier layout (uints): layer L at L*1024:
  //   group g (0..7) at +g*32 (128B apart), master at +256, epoch at +512
  uint32_t* const barL   = bar + (is1 ? 1024 : 0);
  uint32_t* const grpC   = barL + (blk & 7) * 32;
  uint32_t* const mstC   = barL + 256;
  uint32_t* const epoL   = barL + 512;
  uint32_t* const epoO   = bar + (is1 ? 0 : 1024) + 512;

  // B fragments (64 KB) resident in registers
  short8 bfr[64];
  {
    const short8* pB = ((const short8*)Bp) + (size_t)wgid * 4096 + lane;
#pragma unroll
    for (int f = 0; f < 64; ++f) bfr[f] = pB[f * 64];
  }
  const float* bias = is1 ? b1 : b0;
  const float bv = bias[(cc >> 2) * 1024 + n0w + (cc & 3)];

  float cst[8], hst[8];
#pragma unroll
  for (int i = 0; i < 8; ++i) { cst[i] = 0.f; hst[i] = 0.f; }

  const int shuf_base = (lane & 48) | (lane & 3);
  const short8* Xq = (const short8*)Xb;
  const short8* H0 = (const short8*)h0r;
  const short8* H1 = (const short8*)h1b;

  short8* const ldsW = stg + wv * 2048;           // this wave's staging base

  // layer0's h0(255) is consumed by nobody -> it stops after step 254.
  const int tmax = is1 ? TT : (TT - 1);

  for (int t = 0; t < tmax; ++t) {
    const int p  = t & 1;              // h1 ping-pong read parity; write 1-p
    const int rs = (t + 127) & 127;    // h0 ring read slot = (t-1) mod 128

    const short8* pan;
    if (!is1) pan = (wv < 2) ? (Xq + (size_t)t * 4096) : (H0 + (size_t)rs * 4096);
    else      pan = (wv < 2) ? (H0 + (size_t)rs * 4096) : (H1 + p * 4096);

    float mrow[8];
#pragma unroll
    for (int i = 0; i < 8; ++i) {
      int r = ((i >> 2) << 4) + quad * 4 + (i & 3);
      mrow[i] = mask[r * 256 + t];
    }

    // ---- stage this wave's 32KB A-half into LDS (register-free DMA) ----
    {
      const short8* gsrc = pan + kb0 * 32 + lane;  // per-lane global source
      if (coh) {
#pragma unroll
        for (int i = 0; i < 32; ++i) stage_coh(gsrc + i * 64, ldsW + i * 64);
      } else {
#pragma unroll
        for (int i = 0; i < 32; ++i) stage_pln(gsrc + i * 64, ldsW + i * 64);
      }
      asm volatile("s_waitcnt vmcnt(0)" ::: "memory");
      __builtin_amdgcn_sched_barrier(0);
    }

    f32x4 acc[4][2];
#pragma unroll
    for (int cg = 0; cg < 4; ++cg) { acc[cg][0] = (f32x4)0.f; acc[cg][1] = (f32x4)0.f; }

#pragma unroll
    for (int s = 0; s < 16; ++s) {
      short8 a0 = ldsW[(s * 4 + quad) * 32 + cc];        // rows 0..15
      short8 a1 = ldsW[(s * 4 + quad) * 32 + cc + 16];   // rows 16..31
#pragma unroll
      for (int cg = 0; cg < 4; ++cg) {
        acc[cg][0] = __builtin_amdgcn_mfma_f32_16x16x32_bf16(a0, bfr[cg * 16 + s], acc[cg][0], 0, 0, 0);
        acc[cg][1] = __builtin_amdgcn_mfma_f32_16x16x32_bf16(a1, bfr[cg * 16 + s], acc[cg][1], 0, 0, 0);
      }
    }

    // ---- cross-wave K-reduction via LDS (xch overlays stg[0..32KB)) ----
    __syncthreads();   // sync#0: all staged reads done before xch overwrite
#pragma unroll
    for (int cg = 0; cg < 4; ++cg) {
      if (cg != wv) {
        (*(xch + wv))[cg][0][lane] = acc[cg][0];
        (*(xch + wv))[cg][1][lane] = acc[cg][1];
      }
    }
    __syncthreads();
    f32x4 s0 = acc[wv][0], s1 = acc[wv][1];
#pragma unroll
    for (int w2 = 0; w2 < 4; ++w2) {
      if (w2 != wv) {
        s0 += (*(xch + w2))[wv][0][lane];
        s1 += (*(xch + w2))[wv][1][lane];
      }
    }

    float pv[8];
    pv[0] = s0.x + bv; pv[1] = s0.y + bv; pv[2] = s0.z + bv; pv[3] = s0.w + bv;
    pv[4] = s1.x + bv; pv[5] = s1.y + bv; pv[6] = s1.z + bv; pv[7] = s1.w + bv;

    // ---- gating (C/D: col = lane&15, row = quad*4 + reg) ----
#pragma unroll
    for (int i = 0; i < 8; ++i) {
      float v = pv[i];
      float fg = __shfl(v, shuf_base + 0, 64);
      float ig = __shfl(v, shuf_base + 4, 64);
      float og = __shfl(v, shuf_base + 8, 64);
      float gg = __shfl(v, shuf_base + 12, 64);
      int r = ((i >> 2) << 4) + quad * 4 + (i & 3);
      float m  = mrow[i];
      float om = 1.f - m;
      float sf = 1.f / (1.f + __expf(-fg));
      float si = 1.f / (1.f + __expf(-ig));
      float so = 1.f / (1.f + __expf(-og));
      float e2 = __expf(-2.f * fabsf(gg));
      float tg = (1.f - e2) / (1.f + e2);
      tg = (gg < 0.f) ? -tg : tg;
      float c1 = sf * cst[i] + si * tg;
      c1 = c1 * m + cst[i] * om;
      float ec = __expf(-2.f * fabsf(c1));
      float tc = (1.f - ec) / (1.f + ec);
      tc = (c1 < 0.f) ? -tc : tc;
      float h1 = so * tc;
      h1 = h1 * m + hst[i] * om;
      cst[i] = c1; hst[i] = h1;
      if ((lane & 12) == 0) {   // gate-f lanes: one writer per (h-col, row)
        int hl = wv * 4 + (cc & 3);                 // block-local h-col 0..15
        hstage[(hl >> 3) * 256 + r * 8 + (hl & 7)] = f2bf(h1);
        if (is1) out[((size_t)r * 256 + t) * 1024 + hcol] = h1;
      }
    }

    if (is1 && t == TT - 1) break;   // layer1 final step: no successor

    __syncthreads();   // hstage complete across all waves
    if (wv == 0) {     // packed MALL write-through h store: 16B/lane, 1 op
      short* dst = (is1 ? (h1b + (1 - p) * 32768)
                        : (h0r + (t & 127) * 32768)) + blk * 512 + lane * 8;
      short8 hv = ((const short8*)hstage)[lane];
      asm volatile("global_store_dwordx4 %0, %1, off sc0 sc1"
                   :: "v"(dst), "v"(hv) : "memory");
    }

    // ---- per-layer fan-in barrier (R0 topology), epoch spin, gates ----
    if (tid == 0) {
      // drain wave0's h stores to MALL before the arrival is observable
      asm volatile("s_waitcnt vmcnt(0)" ::: "memory");
      uint32_t old = __hip_atomic_fetch_add(grpC, 1u,
                                            __ATOMIC_RELAXED, __HIP_MEMORY_SCOPE_AGENT);
      if ((old & 7) == 7) {   // last of 8 in group this step
        uint32_t mo = __hip_atomic_fetch_add(mstC, 1u,
                                             __ATOMIC_RELAXED, __HIP_MEMORY_SCOPE_AGENT);
        if ((mo & 7) == 7)    // last group -> publish epoch (write-once line)
          __hip_atomic_store(epoL, (uint32_t)(t + 1),
                             __ATOMIC_RELAXED, __HIP_MEMORY_SCOPE_AGENT);
      }
      if (t + 1 < tmax) {     // skip spins when about to exit
        const uint32_t need = (uint32_t)(t + 1);
        if (is1) {
          // own epoch + l0 epoch polled in the same iteration (1 RTT)
          for (;;) {
            uint32_t eL = __hip_atomic_load(epoL, __ATOMIC_RELAXED, __HIP_MEMORY_SCOPE_AGENT);
            uint32_t eO = __hip_atomic_load(epoO, __ATOMIC_RELAXED, __HIP_MEMORY_SCOPE_AGENT);
            if (eL >= need && eO >= need) break;
            __builtin_amdgcn_s_sleep(2);
          }
        } else if (t >= 127) {
          // ring safety: step t+1 overwrites h0(t-127), last read by l1 step
          // t-126 -> require epoch_l1 >= t-125. Slack ~126 steps.
          const uint32_t needO = (uint32_t)(t - 125);
          for (;;) {
            uint32_t eL = __hip_atomic_load(epoL, __ATOMIC_RELAXED, __HIP_MEMORY_SCOPE_AGENT);
            uint32_t eO = __hip_atomic_load(epoO, __ATOMIC_RELAXED, __HIP_MEMORY_SCOPE_AGENT);
            if (eL >= need && eO >= needO) break;
            __builtin_amdgcn_s_sleep(2);
          }
        } else {
          while (__hip_atomic_load(epoL, __ATOMIC_RELAXED, __HIP_MEMORY_SCOPE_AGENT) < need)
            __builtin_amdgcn_s_sleep(2);
        }
      }
    }
    __syncthreads();
  }
}

// ---------------------------------------------------------------------------
// Workspace layout (bytes):
//   [0, 32MB)            B_packed (512 waves x 64KB bf16)
//   [32MB, 48MB)         X blocked
//   [48MB, 56MB)         h0 ring: 128 slots x 64KB (slot = t & 127)
//   [56MB, 56MB+128KB)   h1 ping-pong (2 x 64KB)
//   [+8KB)               barrier (per layer: 8 group ctrs / master / epoch)
//   k_init zeroes [56MB-64KB, 56MB+136KB) = ring slot 127 + h1 + counters
// ---------------------------------------------------------------------------
extern "C" void kernel_launch(void* const* d_in, const int* in_sizes, int n_in,
                              void* d_out, int out_size, void* d_ws, size_t ws_size,
                              hipStream_t stream) {
  const float* x    = (const float*)d_in[0];
  const float* mask = (const float*)d_in[1];
  const float* Wih0 = (const float*)d_in[2];
  const float* Whh0 = (const float*)d_in[3];
  const float* b0   = (const float*)d_in[4];
  const float* Wih1 = (const float*)d_in[5];
  const float* Whh1 = (const float*)d_in[6];
  const float* b1   = (const float*)d_in[7];
  float* out = (float*)d_out;

  char* ws = (char*)d_ws;
  short*    Bp  = (short*)ws;
  short*    Xb  = (short*)(ws + 33554432);
  short*    h0r = (short*)(ws + 50331648);
  short*    h1b = (short*)(ws + 58720256);
  uint32_t* bar = (uint32_t*)(ws + 58851328);
  uint32_t* z   = (uint32_t*)(ws + 58654720);   // zero region base

  hipLaunchKernelGGL(k_init,  dim3(64),   dim3(256), 0, stream, mask, out, z);
  hipLaunchKernelGGL(k_packw, dim3(8192), dim3(256), 0, stream, Wih0, Whh0, Wih1, Whh1, Bp);
  hipLaunchKernelGGL(k_packx, dim3(4096), dim3(256), 0, stream, x, Xb);
  hipLaunchKernelGGL(k_lstm,  dim3(NBLK), dim3(256), 0, stream,
                     mask, b0, b1, Bp, Xb, h0r, h1b, out, bar);
}